// Round 4
// baseline (508.775 us; speedup 1.0000x reference)
//
#include <hip/hip_runtime.h>
#include <math.h>

// ---------- problem constants ----------
#define BB    16
#define CC    256
#define HH    64
#define WW2   64
#define NHD   8
#define HD    32
#define NT    64
#define NWIN  1024
#define TOK   65536
#define HIDN  1024
#define GKS   9
#define GPAD  4

typedef short bf16x8 __attribute__((ext_vector_type(8)));
typedef float f32x4  __attribute__((ext_vector_type(4)));
typedef unsigned short u16x8 __attribute__((ext_vector_type(8)));

__device__ __forceinline__ float b2f(unsigned short u) {
    return __uint_as_float(((unsigned int)u) << 16);
}
__device__ __forceinline__ unsigned short f2b(float f) {
    unsigned int x = __float_as_uint(f);
    unsigned int r = x + 0x7fffu + ((x >> 16) & 1u);   // RNE
    return (unsigned short)(r >> 16);
}
// packed f32x2 -> bf16x2 (RNE), 1 inst for 2 elements
__device__ __forceinline__ unsigned int cvt_pk_bf16(float lo, float hi) {
    unsigned int r;
    asm("v_cvt_pk_bf16_f32 %0, %1, %2" : "=v"(r) : "v"(lo), "v"(hi));
    return r;
}

// sigmoid-form GELU: gelu(v) = v * sigmoid(2u), u = sqrt(2/pi)(v+0.044715 v^3)
__device__ __forceinline__ float gelu_f(float v) {
    const float w = v * v;
    const float u = v * fmaf(w, -0.1029432f, -2.3022082f);  // -2u*log2(e)
    const float e = __builtin_amdgcn_exp2f(u);
    return v * __builtin_amdgcn_rcpf(1.0f + e);
}

// residual add of two bf16x8 vectors via packed converts
__device__ __forceinline__ u16x8 add_bf8(u16x8 a, u16x8 b) {
    u16x8 o;
#pragma unroll
    for (int j = 0; j < 8; j += 2) {
        const unsigned int p = cvt_pk_bf16(b2f(a[j]) + b2f(b[j]),
                                           b2f(a[j + 1]) + b2f(b[j + 1]));
        o[j] = (unsigned short)p;
        o[j + 1] = (unsigned short)(p >> 16);
    }
    return o;
}

// canonical-param element offsets inside PAR
#define O_N1G  64
#define O_N1B  320
#define O_QKVW 576
#define O_QKVB 197184
#define O_RPB  197952
#define O_PW   199808
#define O_PB   265344
#define O_GW   265600
#define O_GB   286336
#define O_N2G  286592
#define O_N2B  286848
#define O_W1   287104
#define O_B1   549248
#define O_W2   550272
#define O_B2   812416

struct ParTab {
    const void* src[15];
    int n[15];
    int off[15];
};

// ---------------------------------------------------------------------------
// K0: dtype detector
// ---------------------------------------------------------------------------
__global__ __launch_bounds__(256) void k_detect(const unsigned short* __restrict__ x,
                                                int* __restrict__ flag) {
    __shared__ int cnt;
    if (threadIdx.x == 0) cnt = 0;
    __syncthreads();
    const unsigned short u = x[threadIdx.x];
    const int e = (u >> 7) & 0xFF;
    if (e >= 140) atomicAdd(&cnt, 1);
    __syncthreads();
    if (threadIdx.x == 0) *flag = (cnt >= 8) ? 1 : 0;
}

// K0c: canonicalize the 15 parameter tensors into PAR (bf16).
// Q-scale (x4) folded into qkv_w rows 0..255 (t==2) and qkv_b[0..255] (t==3).
__global__ __launch_bounds__(256) void k_conv_par(ParTab tab,
                                                  const int* __restrict__ flag,
                                                  unsigned short* __restrict__ par) {
    const int t = blockIdx.y;
    const int n = tab.n[t], off = tab.off[t];
    const bool f32 = (*flag != 0);
    const bool scaled = (t == 2) || (t == 3);
    const int slim = (t == 2) ? 65536 : 256;
    for (int i = blockIdx.x * 256 + threadIdx.x; i < n; i += 64 * 256) {
        unsigned short r;
        if (f32) {
            float v = ((const float*)tab.src[t])[i];
            if (scaled && i < slim) v *= 4.0f;
            r = f2b(v);
        } else {
            r = ((const unsigned short*)tab.src[t])[i];
            if (scaled && i < slim) r = f2b(b2f(r) * 4.0f);
        }
        par[off + i] = r;
    }
}

// ---------------------------------------------------------------------------
// K1: fused transpose/window-partition + LayerNorm1.
// XCD-chunked window map: each XCD owns 128 contiguous windows, so the two
// 32-B halves of each 64-B input line (adjacent ww windows) meet in one L2.
// float4 / uint4 staging loads; packed u32 LDS stores (pad 66 keeps them
// 4-B aligned and the reduce/writeout loops 2-lanes-per-bank = free).
// ---------------------------------------------------------------------------
__global__ __launch_bounds__(256) void k_pre(const void* __restrict__ xsrc,
                                             const int* __restrict__ flag,
                                             const unsigned short* __restrict__ g,
                                             const unsigned short* __restrict__ bt,
                                             unsigned short* __restrict__ SC,
                                             unsigned short* __restrict__ XN) {
    __shared__ __align__(16) unsigned short xs[256 * 66];
    __shared__ float ps[4][64], ps2[4][64];
    __shared__ float mean_s[64], rstd_s[64];
    const int tid = threadIdx.x;
    const int bid = blockIdx.x;
    const int win = (bid & 7) * 128 + (bid >> 3);      // XCD-chunked
    const int b = win >> 6, wh = (win >> 3) & 7, ww = win & 7;
    const bool f32 = (*flag != 0);

    if (f32) {
        for (int idx = tid; idx < 4096; idx += 256) {
            const int c = idx >> 4, u = idx & 15;       // u: 4-pixel unit
            const int h = wh * 8 + (u >> 1), w = ww * 8 + (u & 1) * 4;
            const float4 v = *(const float4*)
                &((const float*)xsrc)[((size_t)(b * CC + c) * HH + h) * WW2 + w];
            unsigned int* dst = (unsigned int*)&xs[c * 66 + u * 4];
            dst[0] = cvt_pk_bf16(v.x, v.y);
            dst[1] = cvt_pk_bf16(v.z, v.w);
        }
    } else {
        for (int idx = tid; idx < 2048; idx += 256) {
            const int c = idx >> 3, u = idx & 7;        // u: 8-pixel row
            const int h = wh * 8 + u, w = ww * 8;
            const uint4 v = *(const uint4*)
                &((const unsigned short*)xsrc)[((size_t)(b * CC + c) * HH + h) * WW2 + w];
            unsigned int* dst = (unsigned int*)&xs[c * 66 + u * 8];
            dst[0] = v.x; dst[1] = v.y; dst[2] = v.z; dst[3] = v.w;
        }
    }
    __syncthreads();
    {
        const int tok = tid & 63, part = tid >> 6;
        float s = 0.f, s2 = 0.f;
        for (int c = part * 64; c < part * 64 + 64; ++c) {
            const float v = b2f(xs[c * 66 + tok]);
            s += v; s2 += v * v;
        }
        ps[part][tok] = s; ps2[part][tok] = s2;
    }
    __syncthreads();
    if (tid < 64) {
        const float s  = ps[0][tid] + ps[1][tid] + ps[2][tid] + ps[3][tid];
        const float s2 = ps2[0][tid] + ps2[1][tid] + ps2[2][tid] + ps2[3][tid];
        const float mean = s * (1.f / 256.f);
        const float var  = s2 * (1.f / 256.f) - mean * mean;
        mean_s[tid] = mean;
        rstd_s[tid] = rsqrtf(var + 1e-5f);
    }
    __syncthreads();
    for (int idx = tid; idx < 16384; idx += 256) {
        const int n = idx >> 8, c = idx & 255;
        const unsigned short raw = xs[c * 66 + n];
        const float v = (b2f(raw) - mean_s[n]) * rstd_s[n] * b2f(g[c]) + b2f(bt[c]);
        const size_t o = (size_t)(win * NT + n) * CC + c;
        SC[o] = raw;
        XN[o] = f2b(v);
    }
}

// ---------------------------------------------------------------------------
// 128x128-tile MFMA GEMM core. Caller passes m0/n0 (XCD-chunked decode).
// T2 XOR swizzle both-sides. Epilogue: reg bias, ACT template, packed bf16
// converts, LDS restage for 16B stores.
// ---------------------------------------------------------------------------
template <int KDIM, int ACT, typename PostF>
__device__ __forceinline__ void gemm128(const unsigned short* __restrict__ A,
                                        const unsigned short* __restrict__ Bw,
                                        const unsigned short* __restrict__ bias,
                                        int m0, int n0, PostF post8) {
    __shared__ __align__(16) unsigned short smem[128 * 136];   // 34 KB
    unsigned short* As = smem;            // [128][64]
    unsigned short* Bs = smem + 8192;     // [128][64]
    const int tid = threadIdx.x;
    const int wv = tid >> 6, ln = tid & 63;
    const int wm = wv & 1, wn = wv >> 1;

    float bias_v[4];
#pragma unroll
    for (int nt = 0; nt < 4; ++nt)
        bias_v[nt] = b2f(bias[n0 + wn * 64 + nt * 16 + (ln & 15)]);

    f32x4 acc[4][4] = {};
    const int u = tid;

    for (int kb = 0; kb < KDIM; kb += 64) {
#pragma unroll
        for (int i = 0; i < 4; ++i) {
            const int uu = i * 256 + u;
            const int row = uu >> 3;
            const int c8 = ((uu & 7) ^ (row & 7)) * 8;   // inverse-swizzled src col
            __builtin_amdgcn_global_load_lds(
                (const __attribute__((address_space(1))) unsigned int*)
                    &A[(size_t)(m0 + row) * KDIM + kb + c8],
                (__attribute__((address_space(3))) unsigned int*)&As[uu * 8],
                16, 0, 0);
            __builtin_amdgcn_global_load_lds(
                (const __attribute__((address_space(1))) unsigned int*)
                    &Bw[(size_t)(n0 + row) * KDIM + kb + c8],
                (__attribute__((address_space(3))) unsigned int*)&Bs[uu * 8],
                16, 0, 0);
        }
        __syncthreads();
#pragma unroll
        for (int ks = 0; ks < 2; ++ks) {
            bf16x8 af[4], bf[4];
            const int sl = ks * 4 + (ln >> 4);           // 16B slot index 0..7
#pragma unroll
            for (int t = 0; t < 4; ++t) {
                const int ra = wm * 64 + t * 16 + (ln & 15);
                const int rb = wn * 64 + t * 16 + (ln & 15);
                af[t] = *(const bf16x8*)&As[ra * 64 + ((sl ^ (ra & 7)) * 8)];
                bf[t] = *(const bf16x8*)&Bs[rb * 64 + ((sl ^ (rb & 7)) * 8)];
            }
#pragma unroll
            for (int mt = 0; mt < 4; ++mt)
#pragma unroll
                for (int nt = 0; nt < 4; ++nt)
                    acc[mt][nt] = __builtin_amdgcn_mfma_f32_16x16x32_bf16(af[mt], bf[nt], acc[mt][nt], 0, 0, 0);
        }
        __syncthreads();
    }

    // epilogue: bias + act -> packed bf16 -> LDS (rows padded to 136) -> 16B stores
    unsigned short* Cs = smem;
#pragma unroll
    for (int mt = 0; mt < 4; ++mt)
#pragma unroll
        for (int nt = 0; nt < 4; ++nt) {
            float v[4];
#pragma unroll
            for (int r = 0; r < 4; ++r) {
                float x = acc[mt][nt][r] + bias_v[nt];
                if (ACT == 1) x = gelu_f(x);
                v[r] = x;
            }
            const int mlb = wm * 64 + mt * 16 + (ln >> 4) * 4;
            const int nl = wn * 64 + nt * 16 + (ln & 15);
            const unsigned int p0 = cvt_pk_bf16(v[0], v[1]);
            const unsigned int p1 = cvt_pk_bf16(v[2], v[3]);
            Cs[(mlb + 0) * 136 + nl] = (unsigned short)p0;
            Cs[(mlb + 1) * 136 + nl] = (unsigned short)(p0 >> 16);
            Cs[(mlb + 2) * 136 + nl] = (unsigned short)p1;
            Cs[(mlb + 3) * 136 + nl] = (unsigned short)(p1 >> 16);
        }
    __syncthreads();
#pragma unroll
    for (int i = 0; i < 8; ++i) {
        const int j = i * 256 + tid;
        const int row = j >> 4, c8 = (j & 15) * 8;
        const u16x8 vals = *(const u16x8*)&Cs[row * 136 + c8];
        post8(m0 + row, n0 + c8, vals);
    }
}

// XCD-chunked tile decode: each XCD (wgid%8) owns a contiguous chunk of 64
// m-tiles and iterates its n-tiles fastest -> A-tile reused from that XCD's
// private L2, W panel L2-resident.
__device__ __forceinline__ void xcd_tiles(int wgid, int NN, int& m0, int& n0) {
    const int xcd = wgid & 7, local = wgid >> 3;
    m0 = (xcd * 64 + local / NN) * 128;
    n0 = (local % NN) * 128;
}

// ---------------------------------------------------------------------------
// K2: QKV GEMM -> Q(pre-scaled),K,V  token-major [65536][256]
// ---------------------------------------------------------------------------
__global__ __launch_bounds__(256) void k_gemm_qkv(const unsigned short* __restrict__ XN,
                                                  const unsigned short* __restrict__ Wq,
                                                  const unsigned short* __restrict__ bq,
                                                  unsigned short* __restrict__ Q,
                                                  unsigned short* __restrict__ K,
                                                  unsigned short* __restrict__ V) {
    int m0, n0;
    xcd_tiles(blockIdx.x, 6, m0, n0);
    gemm128<256, 0>(XN, Wq, bq, m0, n0,
        [&](int m, int nb, u16x8 vals) {
            unsigned short* dst = (nb < 256) ? Q : ((nb < 512) ? K : V);
            *(u16x8*)&dst[(size_t)m * CC + (nb & 255)] = vals;
        });
}

// ---------------------------------------------------------------------------
// K3: window attention (block per (window, head)); Q/K/V token-major
// ---------------------------------------------------------------------------
__global__ __launch_bounds__(256) void k_attn(const unsigned short* __restrict__ Q,
                                              const unsigned short* __restrict__ K,
                                              const unsigned short* __restrict__ V,
                                              const unsigned short* __restrict__ rpb,
                                              unsigned short* __restrict__ AO) {
    __shared__ __align__(16) unsigned short Pb[64 * 72];
    __shared__ __align__(16) unsigned short Vt[32 * 72];
    const int tid = threadIdx.x, wv = tid >> 6, ln = tid & 63;
    const int win = blockIdx.x, head = blockIdx.y;
    const size_t tbase = (size_t)(win * NT) * CC + head * HD;

    {   // vectorized V stage: one u16x8 load per thread, transpose into Vt
        const int tok = tid >> 2, d8 = (tid & 3) * 8;
        const u16x8 vv = *(const u16x8*)&V[tbase + (size_t)tok * CC + d8];
#pragma unroll
        for (int j = 0; j < 8; ++j) Vt[(d8 + j) * 72 + tok] = vv[j];
    }

    const bf16x8 a = *(const bf16x8*)&Q[tbase + (size_t)(16 * wv + (ln & 15)) * CC + (ln >> 4) * 8];
    f32x4 accs[4] = {};
#pragma unroll
    for (int f = 0; f < 4; ++f) {
        const bf16x8 b = *(const bf16x8*)&K[tbase + (size_t)(f * 16 + (ln & 15)) * CC + (ln >> 4) * 8];
        accs[f] = __builtin_amdgcn_mfma_f32_16x16x32_bf16(a, b, accs[f], 0, 0, 0);
    }
    const int qloc = (ln >> 4) * 4;
#pragma unroll
    for (int f = 0; f < 4; ++f)
#pragma unroll
        for (int r = 0; r < 4; ++r) {
            const int rr = 16 * wv + qloc + r;
            const int cth = f * 16 + (ln & 15);
            const int bidx = ((rr >> 3) - (cth >> 3) + 7) * 15 + ((rr & 7) - (cth & 7) + 7);
            accs[f][r] += b2f(rpb[bidx * NHD + head]);
        }
#pragma unroll
    for (int r = 0; r < 4; ++r) {
        float m = fmaxf(fmaxf(accs[0][r], accs[1][r]), fmaxf(accs[2][r], accs[3][r]));
#pragma unroll
        for (int o = 1; o <= 8; o <<= 1) m = fmaxf(m, __shfl_xor(m, o));
        float p[4], s = 0.f;
#pragma unroll
        for (int f = 0; f < 4; ++f) { p[f] = expf(accs[f][r] - m); s += p[f]; }
#pragma unroll
        for (int o = 1; o <= 8; o <<= 1) s += __shfl_xor(s, o);
        const float inv = 1.f / s;
#pragma unroll
        for (int f = 0; f < 4; ++f)
            Pb[(16 * wv + qloc + r) * 72 + f * 16 + (ln & 15)] = f2b(p[f] * inv);
    }
    __syncthreads();

    f32x4 acco[2] = {};
#pragma unroll
    for (int kb = 0; kb < 64; kb += 32) {
        const bf16x8 ap = *(const bf16x8*)&Pb[(16 * wv + (ln & 15)) * 72 + kb + (ln >> 4) * 8];
#pragma unroll
        for (int f = 0; f < 2; ++f) {
            const bf16x8 bv = *(const bf16x8*)&Vt[(f * 16 + (ln & 15)) * 72 + kb + (ln >> 4) * 8];
            acco[f] = __builtin_amdgcn_mfma_f32_16x16x32_bf16(ap, bv, acco[f], 0, 0, 0);
        }
    }
#pragma unroll
    for (int f = 0; f < 2; ++f)
#pragma unroll
        for (int r = 0; r < 4; ++r) {
            const int rr = 16 * wv + qloc + r;
            const int d = f * 16 + (ln & 15);
            AO[tbase + (size_t)rr * CC + d] = f2b(acco[f][r]);
        }
}

// ---------------------------------------------------------------------------
// K4: gaze depthwise 9x9 — LDS-tiled register sliding window (V token-major)
// ---------------------------------------------------------------------------
__global__ __launch_bounds__(256) void k_gaze(const unsigned short* __restrict__ V,
                                              const unsigned short* __restrict__ gw,
                                              const unsigned short* __restrict__ gb,
                                              unsigned short* __restrict__ AO) {
    __shared__ __align__(16) unsigned short ins[24 * 16 * 32];
    __shared__ __align__(16) unsigned short wlds[81 * 32];
    const int tid = threadIdx.x;
    const int c0 = blockIdx.x * 8, r0 = blockIdx.y * 16;
    const int b = blockIdx.z >> 3, head = blockIdx.z & 7;

    for (int idx = tid; idx < 1536; idx += 256) {
        const int pix = idx >> 2, v4 = (idx & 3) * 8;
        const int row = pix >> 4, colL = pix & 15;
        const int rp = r0 + row - GPAD, cp = c0 + colL - GPAD;
        uint4 val = {0, 0, 0, 0};
        if (rp >= 0 && rp < HH && cp >= 0 && cp < WW2) {
            const int win = b * 64 + (rp & 7) * 8 + (cp & 7);
            const int n = (rp >> 3) * 8 + (cp >> 3);
            val = *(const uint4*)&V[(size_t)(win * NT + n) * CC + head * HD + v4];
        }
        *(uint4*)&ins[(row * 16 + colL) * 32 + v4] = val;
    }
    for (int idx = tid; idx < 324; idx += 256) {
        const int k = idx >> 2, v4 = (idx & 3) * 8;
        *(uint4*)&wlds[k * 32 + v4] = *(const uint4*)&gw[k * CC + head * HD + v4];
    }
    __syncthreads();

    const int d = tid & 31;
    const int col = tid >> 5;
    float out[16];
#pragma unroll
    for (int ro = 0; ro < 16; ++ro) out[ro] = 0.f;

#pragma unroll
    for (int dx = 0; dx < GKS; ++dx) {
        float wreg[GKS];
#pragma unroll
        for (int dy = 0; dy < GKS; ++dy)
            wreg[dy] = b2f(wlds[(dy * GKS + dx) * 32 + d]);
        float inreg[24];
#pragma unroll
        for (int ri = 0; ri < 24; ++ri)
            inreg[ri] = b2f(ins[(ri * 16 + col + dx) * 32 + d]);
#pragma unroll
        for (int ro = 0; ro < 16; ++ro)
#pragma unroll
            for (int dy = 0; dy < GKS; ++dy)
                out[ro] = fmaf(inreg[ro + dy], wreg[dy], out[ro]);
    }

    const float bias = b2f(gb[head * HD + d]);
    const int c = c0 + col;
#pragma unroll
    for (int ro = 0; ro < 16; ++ro) {
        const int r = r0 + ro;
        const int win0 = b * 64 + (r & 7) * 8 + (c & 7);
        const int n0 = (r >> 3) * 8 + (c >> 3);
        const size_t o = (size_t)(win0 * NT + n0) * CC + head * HD + d;
        AO[o] = f2b(b2f(AO[o]) + out[ro] + bias);
    }
}

// ---------------------------------------------------------------------------
// K5: proj GEMM + shortcut residual (SC, coalesced) -> X2 bf16
// ---------------------------------------------------------------------------
__global__ __launch_bounds__(256) void k_gemm_proj(const unsigned short* __restrict__ AO,
                                                   const unsigned short* __restrict__ Wp,
                                                   const unsigned short* __restrict__ bp,
                                                   const unsigned short* __restrict__ SC,
                                                   unsigned short* __restrict__ X2) {
    int m0, n0;
    xcd_tiles(blockIdx.x, 2, m0, n0);
    gemm128<256, 0>(AO, Wp, bp, m0, n0,
        [&](int m, int nb, u16x8 vals) {
            const u16x8 sc = *(const u16x8*)&SC[(size_t)m * CC + nb];
            *(u16x8*)&X2[(size_t)m * CC + nb] = add_bf8(vals, sc);
        });
}

// ---------------------------------------------------------------------------
// K6: LayerNorm2 — vectorized: half-wave per token, u16x8 loads/stores
// ---------------------------------------------------------------------------
__global__ __launch_bounds__(256) void k_ln2(const unsigned short* __restrict__ X2,
                                             const unsigned short* __restrict__ g,
                                             const unsigned short* __restrict__ bt,
                                             unsigned short* __restrict__ X2N) {
    const int tid = threadIdx.x;
    const int wv = tid >> 6, ln = tid & 63;
    const int t = blockIdx.x * 8 + wv * 2 + (ln >> 5);
    const int c8 = (ln & 31) * 8;
    const u16x8 xv = *(const u16x8*)&X2[(size_t)t * CC + c8];
    float vals[8];
    float s = 0.f, s2 = 0.f;
#pragma unroll
    for (int j = 0; j < 8; ++j) {
        const float v = b2f(xv[j]);
        vals[j] = v; s += v; s2 += v * v;
    }
#pragma unroll
    for (int off = 16; off; off >>= 1) {       // reduce within 32-lane half
        s += __shfl_xor(s, off);
        s2 += __shfl_xor(s2, off);
    }
    const float mean = s * (1.f / 256.f);
    const float rstd = rsqrtf(s2 * (1.f / 256.f) - mean * mean + 1e-5f);
    const u16x8 gv = *(const u16x8*)&g[c8];
    const u16x8 bv = *(const u16x8*)&bt[c8];
    u16x8 o;
#pragma unroll
    for (int j = 0; j < 8; j += 2) {
        const float a0 = (vals[j] - mean) * rstd * b2f(gv[j]) + b2f(bv[j]);
        const float a1 = (vals[j + 1] - mean) * rstd * b2f(gv[j + 1]) + b2f(bv[j + 1]);
        const unsigned int p = cvt_pk_bf16(a0, a1);
        o[j] = (unsigned short)p;
        o[j + 1] = (unsigned short)(p >> 16);
    }
    *(u16x8*)&X2N[(size_t)t * CC + c8] = o;
}

// ---------------------------------------------------------------------------
// K7: fc1 GEMM + GELU -> H1
// ---------------------------------------------------------------------------
__global__ __launch_bounds__(256) void k_gemm_fc1(const unsigned short* __restrict__ X2N,
                                                  const unsigned short* __restrict__ W1,
                                                  const unsigned short* __restrict__ b1,
                                                  unsigned short* __restrict__ H1) {
    int m0, n0;
    xcd_tiles(blockIdx.x, 8, m0, n0);
    gemm128<256, 1>(X2N, W1, b1, m0, n0,
        [&](int m, int nb, u16x8 vals) {
            *(u16x8*)&H1[(size_t)m * HIDN + nb] = vals;
        });
}

// ---------------------------------------------------------------------------
// K8: fc2 GEMM + trunk residual -> XOUT
// ---------------------------------------------------------------------------
__global__ __launch_bounds__(256) void k_gemm_fc2(const unsigned short* __restrict__ H1,
                                                  const unsigned short* __restrict__ W2,
                                                  const unsigned short* __restrict__ b2v,
                                                  const unsigned short* __restrict__ X2,
                                                  unsigned short* __restrict__ XOUT) {
    int m0, n0;
    xcd_tiles(blockIdx.x, 2, m0, n0);
    gemm128<1024, 0>(H1, W2, b2v, m0, n0,
        [&](int m, int nb, u16x8 vals) {
            const u16x8 r = *(const u16x8*)&X2[(size_t)m * CC + nb];
            *(u16x8*)&XOUT[(size_t)m * CC + nb] = add_bf8(vals, r);
        });
}

// ---------------------------------------------------------------------------
// K9: window reverse + transpose to (B,C,H,W). XCD-chunked window map (write
// halves of each 64-B out line meet in one XCD's L2 / write-combine), and
// vectorized: u16x8 staging loads, float4 / u16x8 output stores.
// ---------------------------------------------------------------------------
__global__ __launch_bounds__(256) void k_out(const unsigned short* __restrict__ XOUT,
                                             const int* __restrict__ flag,
                                             void* __restrict__ out) {
    __shared__ __align__(16) unsigned short ys[64 * 257];
    const int tid = threadIdx.x;
    const int bid = blockIdx.x;
    const int win = (bid & 7) * 128 + (bid >> 3);      // XCD-chunked
    const int b = win >> 6, wh = (win >> 3) & 7, ww = win & 7;
    for (int idx = tid; idx < 2048; idx += 256) {
        const int n = idx >> 5, c8 = (idx & 31) * 8;
        const u16x8 v = *(const u16x8*)&XOUT[(size_t)(win * NT + n) * CC + c8];
#pragma unroll
        for (int j = 0; j < 8; ++j) ys[n * 257 + c8 + j] = v[j];
    }
    __syncthreads();
    const bool f32 = (*flag != 0);
    if (f32) {
        for (int idx = tid; idx < 4096; idx += 256) {
            const int ch = idx >> 4, u = idx & 15;      // u: 4-pixel unit
            const int h = wh * 8 + (u >> 1), w = ww * 8 + (u & 1) * 4;
            const int n0 = u * 4;
            float4 v;
            v.x = b2f(ys[(n0 + 0) * 257 + ch]);
            v.y = b2f(ys[(n0 + 1) * 257 + ch]);
            v.z = b2f(ys[(n0 + 2) * 257 + ch]);
            v.w = b2f(ys[(n0 + 3) * 257 + ch]);
            *(float4*)&((float*)out)[((size_t)(b * CC + ch) * HH + h) * WW2 + w] = v;
        }
    } else {
        for (int idx = tid; idx < 2048; idx += 256) {
            const int ch = idx >> 3, u = idx & 7;       // u: 8-pixel row
            const int h = wh * 8 + u, w = ww * 8;
            const int n0 = u * 8;
            u16x8 v;
#pragma unroll
            for (int j = 0; j < 8; ++j) v[j] = ys[(n0 + j) * 257 + ch];
            *(u16x8*)&((unsigned short*)out)[((size_t)(b * CC + ch) * HH + h) * WW2 + w] = v;
        }
    }
}

// ---------------------------------------------------------------------------
extern "C" void kernel_launch(void* const* d_in, const int* in_sizes, int n_in,
                              void* d_out, int out_size, void* d_ws, size_t ws_size,
                              hipStream_t stream) {
    char* ws = (char*)d_ws;
    const size_t MB = 1048576;
    unsigned short* SC  = (unsigned short*)(ws);
    unsigned short* XN  = (unsigned short*)(ws + 32 * MB);
    unsigned short* Qb  = (unsigned short*)(ws + 64 * MB);
    unsigned short* Kb  = (unsigned short*)(ws + 96 * MB);
    unsigned short* Vb  = (unsigned short*)(ws + 128 * MB);
    unsigned short* AO  = (unsigned short*)(ws + 160 * MB);
    unsigned short* H1  = (unsigned short*)(ws + 64 * MB);
    unsigned short* X2  = (unsigned short*)(ws + 192 * MB);
    unsigned short* PAR = (unsigned short*)(ws + 224 * MB);
    int* FLAG = (int*)(ws + 224 * MB);
    unsigned short* X2N  = XN;
    unsigned short* XOUT = XN;

    ParTab tab;
    const int srcidx[15] = {3, 4, 5, 6, 7, 8, 9, 10, 11, 12, 13, 14, 15, 16, 17};
    const int sizes[15]  = {256, 256, 196608, 768, 1800, 65536, 256, 20736, 256,
                            256, 256, 262144, 1024, 262144, 256};
    const int offs[15]   = {O_N1G, O_N1B, O_QKVW, O_QKVB, O_RPB, O_PW, O_PB, O_GW, O_GB,
                            O_N2G, O_N2B, O_W1, O_B1, O_W2, O_B2};
    for (int i = 0; i < 15; ++i) {
        tab.src[i] = d_in[srcidx[i]];
        tab.n[i] = sizes[i];
        tab.off[i] = offs[i];
    }

    k_detect   <<<1,                 256, 0, stream>>>((const unsigned short*)d_in[2], FLAG);
    k_conv_par <<<dim3(64, 15),      256, 0, stream>>>(tab, FLAG, PAR);
    k_pre      <<<NWIN,              256, 0, stream>>>(d_in[2], FLAG, PAR + O_N1G, PAR + O_N1B, SC, XN);
    k_gemm_qkv <<<3072,              256, 0, stream>>>(XN, PAR + O_QKVW, PAR + O_QKVB, Qb, Kb, Vb);
    k_attn     <<<dim3(NWIN, NHD),   256, 0, stream>>>(Qb, Kb, Vb, PAR + O_RPB, AO);
    k_gaze     <<<dim3(8, 4, 128),   256, 0, stream>>>(Vb, PAR + O_GW, PAR + O_GB, AO);
    k_gemm_proj<<<1024,              256, 0, stream>>>(AO, PAR + O_PW, PAR + O_PB, SC, X2);
    k_ln2      <<<TOK / 8,           256, 0, stream>>>(X2, PAR + O_N2G, PAR + O_N2B, X2N);
    k_gemm_fc1 <<<4096,              256, 0, stream>>>(X2N, PAR + O_W1, PAR + O_B1, H1);
    k_gemm_fc2 <<<1024,              256, 0, stream>>>(H1, PAR + O_W2, PAR + O_B2, X2, XOUT);
    k_out      <<<NWIN,              256, 0, stream>>>(XOUT, FLAG, d_out);
}

// Round 5
// 474.467 us; speedup vs baseline: 1.0723x; 1.0723x over previous
//
#include <hip/hip_runtime.h>
#include <math.h>

// ---------- problem constants ----------
#define BB    16
#define CC    256
#define HH    64
#define WW2   64
#define NHD   8
#define HD    32
#define NT    64
#define NWIN  1024
#define TOK   65536
#define HIDN  1024
#define GKS   9
#define GPAD  4

typedef short bf16x8 __attribute__((ext_vector_type(8)));
typedef float f32x4  __attribute__((ext_vector_type(4)));
typedef float f32x2  __attribute__((ext_vector_type(2)));
typedef unsigned short u16x8 __attribute__((ext_vector_type(8)));

__device__ __forceinline__ float b2f(unsigned short u) {
    return __uint_as_float(((unsigned int)u) << 16);
}
__device__ __forceinline__ unsigned short f2b(float f) {
    unsigned int x = __float_as_uint(f);
    unsigned int r = x + 0x7fffu + ((x >> 16) & 1u);   // RNE
    return (unsigned short)(r >> 16);
}
// packed f32x2 -> bf16x2 (RNE), 1 inst for 2 elements
__device__ __forceinline__ unsigned int cvt_pk_bf16(float lo, float hi) {
    unsigned int r;
    asm("v_cvt_pk_bf16_f32 %0, %1, %2" : "=v"(r) : "v"(lo), "v"(hi));
    return r;
}
// 2 packed bf16 (u32) -> f32x2, 2 insts
__device__ __forceinline__ f32x2 bf2_to_f32x2(unsigned int u) {
    f32x2 r;
    r.x = __uint_as_float(u << 16);
    r.y = __uint_as_float(u & 0xFFFF0000u);
    return r;
}

// sigmoid-form GELU: gelu(v) = v * sigmoid(2u), u = sqrt(2/pi)(v+0.044715 v^3)
__device__ __forceinline__ float gelu_f(float v) {
    const float w = v * v;
    const float u = v * fmaf(w, -0.1029432f, -2.3022082f);  // -2u*log2(e)
    const float e = __builtin_amdgcn_exp2f(u);
    return v * __builtin_amdgcn_rcpf(1.0f + e);
}

// residual add of two bf16x8 vectors via packed converts
__device__ __forceinline__ u16x8 add_bf8(u16x8 a, u16x8 b) {
    u16x8 o;
#pragma unroll
    for (int j = 0; j < 8; j += 2) {
        const unsigned int p = cvt_pk_bf16(b2f(a[j]) + b2f(b[j]),
                                           b2f(a[j + 1]) + b2f(b[j + 1]));
        o[j] = (unsigned short)p;
        o[j + 1] = (unsigned short)(p >> 16);
    }
    return o;
}

// canonical-param element offsets inside PAR
#define O_N1G  64
#define O_N1B  320
#define O_QKVW 576
#define O_QKVB 197184
#define O_RPB  197952
#define O_PW   199808
#define O_PB   265344
#define O_GW   265600
#define O_GB   286336
#define O_N2G  286592
#define O_N2B  286848
#define O_W1   287104
#define O_B1   549248
#define O_W2   550272
#define O_B2   812416

struct ParTab {
    const void* src[15];
    int n[15];
    int off[15];
};

// ---------------------------------------------------------------------------
// K0: dtype detector
// ---------------------------------------------------------------------------
__global__ __launch_bounds__(256) void k_detect(const unsigned short* __restrict__ x,
                                                int* __restrict__ flag) {
    __shared__ int cnt;
    if (threadIdx.x == 0) cnt = 0;
    __syncthreads();
    const unsigned short u = x[threadIdx.x];
    const int e = (u >> 7) & 0xFF;
    if (e >= 140) atomicAdd(&cnt, 1);
    __syncthreads();
    if (threadIdx.x == 0) *flag = (cnt >= 8) ? 1 : 0;
}

// K0c: canonicalize the 15 parameter tensors into PAR (bf16).
// Q-scale (x4) folded into qkv_w rows 0..255 (t==2) and qkv_b[0..255] (t==3).
__global__ __launch_bounds__(256) void k_conv_par(ParTab tab,
                                                  const int* __restrict__ flag,
                                                  unsigned short* __restrict__ par) {
    const int t = blockIdx.y;
    const int n = tab.n[t], off = tab.off[t];
    const bool f32 = (*flag != 0);
    const bool scaled = (t == 2) || (t == 3);
    const int slim = (t == 2) ? 65536 : 256;
    for (int i = blockIdx.x * 256 + threadIdx.x; i < n; i += 64 * 256) {
        unsigned short r;
        if (f32) {
            float v = ((const float*)tab.src[t])[i];
            if (scaled && i < slim) v *= 4.0f;
            r = f2b(v);
        } else {
            r = ((const unsigned short*)tab.src[t])[i];
            if (scaled && i < slim) r = f2b(b2f(r) * 4.0f);
        }
        par[off + i] = r;
    }
}

// ---------------------------------------------------------------------------
// K1: fused transpose/window-partition + LayerNorm1.
// XCD-chunked window map + vectorized staging.
// ---------------------------------------------------------------------------
__global__ __launch_bounds__(256) void k_pre(const void* __restrict__ xsrc,
                                             const int* __restrict__ flag,
                                             const unsigned short* __restrict__ g,
                                             const unsigned short* __restrict__ bt,
                                             unsigned short* __restrict__ SC,
                                             unsigned short* __restrict__ XN) {
    __shared__ __align__(16) unsigned short xs[256 * 66];
    __shared__ float ps[4][64], ps2[4][64];
    __shared__ float mean_s[64], rstd_s[64];
    const int tid = threadIdx.x;
    const int bid = blockIdx.x;
    const int win = (bid & 7) * 128 + (bid >> 3);      // XCD-chunked
    const int b = win >> 6, wh = (win >> 3) & 7, ww = win & 7;
    const bool f32 = (*flag != 0);

    if (f32) {
        for (int idx = tid; idx < 4096; idx += 256) {
            const int c = idx >> 4, u = idx & 15;       // u: 4-pixel unit
            const int h = wh * 8 + (u >> 1), w = ww * 8 + (u & 1) * 4;
            const float4 v = *(const float4*)
                &((const float*)xsrc)[((size_t)(b * CC + c) * HH + h) * WW2 + w];
            unsigned int* dst = (unsigned int*)&xs[c * 66 + u * 4];
            dst[0] = cvt_pk_bf16(v.x, v.y);
            dst[1] = cvt_pk_bf16(v.z, v.w);
        }
    } else {
        for (int idx = tid; idx < 2048; idx += 256) {
            const int c = idx >> 3, u = idx & 7;        // u: 8-pixel row
            const int h = wh * 8 + u, w = ww * 8;
            const uint4 v = *(const uint4*)
                &((const unsigned short*)xsrc)[((size_t)(b * CC + c) * HH + h) * WW2 + w];
            unsigned int* dst = (unsigned int*)&xs[c * 66 + u * 8];
            dst[0] = v.x; dst[1] = v.y; dst[2] = v.z; dst[3] = v.w;
        }
    }
    __syncthreads();
    {
        const int tok = tid & 63, part = tid >> 6;
        float s = 0.f, s2 = 0.f;
        for (int c = part * 64; c < part * 64 + 64; ++c) {
            const float v = b2f(xs[c * 66 + tok]);
            s += v; s2 += v * v;
        }
        ps[part][tok] = s; ps2[part][tok] = s2;
    }
    __syncthreads();
    if (tid < 64) {
        const float s  = ps[0][tid] + ps[1][tid] + ps[2][tid] + ps[3][tid];
        const float s2 = ps2[0][tid] + ps2[1][tid] + ps2[2][tid] + ps2[3][tid];
        const float mean = s * (1.f / 256.f);
        const float var  = s2 * (1.f / 256.f) - mean * mean;
        mean_s[tid] = mean;
        rstd_s[tid] = rsqrtf(var + 1e-5f);
    }
    __syncthreads();
    for (int idx = tid; idx < 16384; idx += 256) {
        const int n = idx >> 8, c = idx & 255;
        const unsigned short raw = xs[c * 66 + n];
        const float v = (b2f(raw) - mean_s[n]) * rstd_s[n] * b2f(g[c]) + b2f(bt[c]);
        const size_t o = (size_t)(win * NT + n) * CC + c;
        SC[o] = raw;
        XN[o] = f2b(v);
    }
}

// ---------------------------------------------------------------------------
// 128x128-tile MFMA GEMM core. Caller passes m0/n0 (XCD-chunked decode).
// T2 XOR swizzle both-sides. Epilogue: reg bias, ACT template, packed bf16
// converts, LDS restage for 16B stores.
// ---------------------------------------------------------------------------
template <int KDIM, int ACT, typename PostF>
__device__ __forceinline__ void gemm128(const unsigned short* __restrict__ A,
                                        const unsigned short* __restrict__ Bw,
                                        const unsigned short* __restrict__ bias,
                                        int m0, int n0, PostF post8) {
    __shared__ __align__(16) unsigned short smem[128 * 136];   // 34 KB
    unsigned short* As = smem;            // [128][64]
    unsigned short* Bs = smem + 8192;     // [128][64]
    const int tid = threadIdx.x;
    const int wv = tid >> 6, ln = tid & 63;
    const int wm = wv & 1, wn = wv >> 1;

    float bias_v[4];
#pragma unroll
    for (int nt = 0; nt < 4; ++nt)
        bias_v[nt] = b2f(bias[n0 + wn * 64 + nt * 16 + (ln & 15)]);

    f32x4 acc[4][4] = {};
    const int u = tid;

    for (int kb = 0; kb < KDIM; kb += 64) {
#pragma unroll
        for (int i = 0; i < 4; ++i) {
            const int uu = i * 256 + u;
            const int row = uu >> 3;
            const int c8 = ((uu & 7) ^ (row & 7)) * 8;   // inverse-swizzled src col
            __builtin_amdgcn_global_load_lds(
                (const __attribute__((address_space(1))) unsigned int*)
                    &A[(size_t)(m0 + row) * KDIM + kb + c8],
                (__attribute__((address_space(3))) unsigned int*)&As[uu * 8],
                16, 0, 0);
            __builtin_amdgcn_global_load_lds(
                (const __attribute__((address_space(1))) unsigned int*)
                    &Bw[(size_t)(n0 + row) * KDIM + kb + c8],
                (__attribute__((address_space(3))) unsigned int*)&Bs[uu * 8],
                16, 0, 0);
        }
        __syncthreads();
#pragma unroll
        for (int ks = 0; ks < 2; ++ks) {
            bf16x8 af[4], bf[4];
            const int sl = ks * 4 + (ln >> 4);           // 16B slot index 0..7
#pragma unroll
            for (int t = 0; t < 4; ++t) {
                const int ra = wm * 64 + t * 16 + (ln & 15);
                const int rb = wn * 64 + t * 16 + (ln & 15);
                af[t] = *(const bf16x8*)&As[ra * 64 + ((sl ^ (ra & 7)) * 8)];
                bf[t] = *(const bf16x8*)&Bs[rb * 64 + ((sl ^ (rb & 7)) * 8)];
            }
#pragma unroll
            for (int mt = 0; mt < 4; ++mt)
#pragma unroll
                for (int nt = 0; nt < 4; ++nt)
                    acc[mt][nt] = __builtin_amdgcn_mfma_f32_16x16x32_bf16(af[mt], bf[nt], acc[mt][nt], 0, 0, 0);
        }
        __syncthreads();
    }

    // epilogue: bias + act -> packed bf16 -> LDS (rows padded to 136) -> 16B stores
    unsigned short* Cs = smem;
#pragma unroll
    for (int mt = 0; mt < 4; ++mt)
#pragma unroll
        for (int nt = 0; nt < 4; ++nt) {
            float v[4];
#pragma unroll
            for (int r = 0; r < 4; ++r) {
                float x = acc[mt][nt][r] + bias_v[nt];
                if (ACT == 1) x = gelu_f(x);
                v[r] = x;
            }
            const int mlb = wm * 64 + mt * 16 + (ln >> 4) * 4;
            const int nl = wn * 64 + nt * 16 + (ln & 15);
            const unsigned int p0 = cvt_pk_bf16(v[0], v[1]);
            const unsigned int p1 = cvt_pk_bf16(v[2], v[3]);
            Cs[(mlb + 0) * 136 + nl] = (unsigned short)p0;
            Cs[(mlb + 1) * 136 + nl] = (unsigned short)(p0 >> 16);
            Cs[(mlb + 2) * 136 + nl] = (unsigned short)p1;
            Cs[(mlb + 3) * 136 + nl] = (unsigned short)(p1 >> 16);
        }
    __syncthreads();
#pragma unroll
    for (int i = 0; i < 8; ++i) {
        const int j = i * 256 + tid;
        const int row = j >> 4, c8 = (j & 15) * 8;
        const u16x8 vals = *(const u16x8*)&Cs[row * 136 + c8];
        post8(m0 + row, n0 + c8, vals);
    }
}

// XCD-chunked tile decode: each XCD (wgid%8) owns a contiguous chunk of 64
// m-tiles and iterates its n-tiles fastest -> A-tile reused from that XCD's
// private L2, W panel L2-resident.
__device__ __forceinline__ void xcd_tiles(int wgid, int NN, int& m0, int& n0) {
    const int xcd = wgid & 7, local = wgid >> 3;
    m0 = (xcd * 64 + local / NN) * 128;
    n0 = (local % NN) * 128;
}

// ---------------------------------------------------------------------------
// K2: QKV GEMM -> Q(pre-scaled),K,V  token-major [65536][256]
// ---------------------------------------------------------------------------
__global__ __launch_bounds__(256) void k_gemm_qkv(const unsigned short* __restrict__ XN,
                                                  const unsigned short* __restrict__ Wq,
                                                  const unsigned short* __restrict__ bq,
                                                  unsigned short* __restrict__ Q,
                                                  unsigned short* __restrict__ K,
                                                  unsigned short* __restrict__ V) {
    int m0, n0;
    xcd_tiles(blockIdx.x, 6, m0, n0);
    gemm128<256, 0>(XN, Wq, bq, m0, n0,
        [&](int m, int nb, u16x8 vals) {
            unsigned short* dst = (nb < 256) ? Q : ((nb < 512) ? K : V);
            *(u16x8*)&dst[(size_t)m * CC + (nb & 255)] = vals;
        });
}

// ---------------------------------------------------------------------------
// K3: window attention (block per (window, head)); Q/K/V token-major
// ---------------------------------------------------------------------------
__global__ __launch_bounds__(256) void k_attn(const unsigned short* __restrict__ Q,
                                              const unsigned short* __restrict__ K,
                                              const unsigned short* __restrict__ V,
                                              const unsigned short* __restrict__ rpb,
                                              unsigned short* __restrict__ AO) {
    __shared__ __align__(16) unsigned short Pb[64 * 72];
    __shared__ __align__(16) unsigned short Vt[32 * 72];
    const int tid = threadIdx.x, wv = tid >> 6, ln = tid & 63;
    const int win = blockIdx.x, head = blockIdx.y;
    const size_t tbase = (size_t)(win * NT) * CC + head * HD;

    {   // vectorized V stage: one u16x8 load per thread, transpose into Vt
        const int tok = tid >> 2, d8 = (tid & 3) * 8;
        const u16x8 vv = *(const u16x8*)&V[tbase + (size_t)tok * CC + d8];
#pragma unroll
        for (int j = 0; j < 8; ++j) Vt[(d8 + j) * 72 + tok] = vv[j];
    }

    const bf16x8 a = *(const bf16x8*)&Q[tbase + (size_t)(16 * wv + (ln & 15)) * CC + (ln >> 4) * 8];
    f32x4 accs[4] = {};
#pragma unroll
    for (int f = 0; f < 4; ++f) {
        const bf16x8 b = *(const bf16x8*)&K[tbase + (size_t)(f * 16 + (ln & 15)) * CC + (ln >> 4) * 8];
        accs[f] = __builtin_amdgcn_mfma_f32_16x16x32_bf16(a, b, accs[f], 0, 0, 0);
    }
    const int qloc = (ln >> 4) * 4;
#pragma unroll
    for (int f = 0; f < 4; ++f)
#pragma unroll
        for (int r = 0; r < 4; ++r) {
            const int rr = 16 * wv + qloc + r;
            const int cth = f * 16 + (ln & 15);
            const int bidx = ((rr >> 3) - (cth >> 3) + 7) * 15 + ((rr & 7) - (cth & 7) + 7);
            accs[f][r] += b2f(rpb[bidx * NHD + head]);
        }
#pragma unroll
    for (int r = 0; r < 4; ++r) {
        float m = fmaxf(fmaxf(accs[0][r], accs[1][r]), fmaxf(accs[2][r], accs[3][r]));
#pragma unroll
        for (int o = 1; o <= 8; o <<= 1) m = fmaxf(m, __shfl_xor(m, o));
        float p[4], s = 0.f;
#pragma unroll
        for (int f = 0; f < 4; ++f) { p[f] = expf(accs[f][r] - m); s += p[f]; }
#pragma unroll
        for (int o = 1; o <= 8; o <<= 1) s += __shfl_xor(s, o);
        const float inv = 1.f / s;
#pragma unroll
        for (int f = 0; f < 4; ++f)
            Pb[(16 * wv + qloc + r) * 72 + f * 16 + (ln & 15)] = f2b(p[f] * inv);
    }
    __syncthreads();

    f32x4 acco[2] = {};
#pragma unroll
    for (int kb = 0; kb < 64; kb += 32) {
        const bf16x8 ap = *(const bf16x8*)&Pb[(16 * wv + (ln & 15)) * 72 + kb + (ln >> 4) * 8];
#pragma unroll
        for (int f = 0; f < 2; ++f) {
            const bf16x8 bv = *(const bf16x8*)&Vt[(f * 16 + (ln & 15)) * 72 + kb + (ln >> 4) * 8];
            acco[f] = __builtin_amdgcn_mfma_f32_16x16x32_bf16(ap, bv, acco[f], 0, 0, 0);
        }
    }
#pragma unroll
    for (int f = 0; f < 2; ++f)
#pragma unroll
        for (int r = 0; r < 4; ++r) {
            const int rr = 16 * wv + qloc + r;
            const int d = f * 16 + (ln & 15);
            AO[tbase + (size_t)rr * CC + d] = f2b(acco[f][r]);
        }
}

// ---------------------------------------------------------------------------
// K4: gaze depthwise 9x9 — packed-fp32 (v_pk_fma_f32) channel-pair version.
// Thread = (col, row-half, channel-pair): 8 outputs x 81 taps = 648 pk_fma.
// Weights staged to LDS pre-converted to f32 pairs (kills per-use converts);
// input tile stays bf16 (occupancy), converted 2-ch-at-a-time on load.
// Register budget: in2[17]+w2[9]+out2[8] = 68 VGPR pairs-worth < 128.
// ---------------------------------------------------------------------------
__global__ __launch_bounds__(256) void k_gaze(const unsigned short* __restrict__ V,
                                              const unsigned short* __restrict__ gw,
                                              const unsigned short* __restrict__ gb,
                                              unsigned short* __restrict__ AO) {
    __shared__ __align__(16) unsigned short ins[24 * 16 * 32];   // 24 KB
    __shared__ __align__(16) float wf[81 * 32];                  // 10.4 KB
    const int tid = threadIdx.x;
    const int c0 = blockIdx.x * 8, r0 = blockIdx.y * 16;
    const int b = blockIdx.z >> 3, head = blockIdx.z & 7;

    for (int idx = tid; idx < 1536; idx += 256) {
        const int pix = idx >> 2, v4 = (idx & 3) * 8;
        const int row = pix >> 4, colL = pix & 15;
        const int rp = r0 + row - GPAD, cp = c0 + colL - GPAD;
        uint4 val = {0, 0, 0, 0};
        if (rp >= 0 && rp < HH && cp >= 0 && cp < WW2) {
            const int win = b * 64 + (rp & 7) * 8 + (cp & 7);
            const int n = (rp >> 3) * 8 + (cp >> 3);
            val = *(const uint4*)&V[(size_t)(win * NT + n) * CC + head * HD + v4];
        }
        *(uint4*)&ins[(row * 16 + colL) * 32 + v4] = val;
    }
    for (int idx = tid; idx < 1296; idx += 256) {
        const int k = idx >> 4, dpair = idx & 15;
        const unsigned int w2u = *(const unsigned int*)&gw[k * CC + head * HD + dpair * 2];
        *(f32x2*)&wf[k * 32 + dpair * 2] = bf2_to_f32x2(w2u);
    }
    __syncthreads();

    const int col  = tid >> 5;          // 0..7
    const int half = (tid >> 4) & 1;    // 0..1 (rows 0-7 / 8-15)
    const int dp   = tid & 15;          // channel pair index
    const int rbase = half * 8;

    f32x2 out2[8];
#pragma unroll
    for (int ro = 0; ro < 8; ++ro) out2[ro] = (f32x2){0.f, 0.f};

#pragma unroll
    for (int dx = 0; dx < GKS; ++dx) {
        f32x2 w2[GKS];
#pragma unroll
        for (int dy = 0; dy < GKS; ++dy)
            w2[dy] = *(const f32x2*)&wf[(dy * GKS + dx) * 32 + dp * 2];
        f32x2 in2[17];
#pragma unroll
        for (int ri = 0; ri < 17; ++ri) {
            const unsigned int u = *(const unsigned int*)
                &ins[((rbase + ri) * 16 + col + dx) * 32 + dp * 2];
            in2[ri] = bf2_to_f32x2(u);
        }
#pragma unroll
        for (int ro = 0; ro < 8; ++ro)
#pragma unroll
            for (int dy = 0; dy < GKS; ++dy)
                asm("v_pk_fma_f32 %0, %1, %2, %0"
                    : "+v"(out2[ro]) : "v"(in2[ro + dy]), "v"(w2[dy]));
    }

    const unsigned int bw = *(const unsigned int*)&gb[head * HD + dp * 2];
    const f32x2 bias2 = bf2_to_f32x2(bw);
    const int c = c0 + col;
#pragma unroll
    for (int ro = 0; ro < 8; ++ro) {
        const int r = r0 + rbase + ro;
        const int win0 = b * 64 + (r & 7) * 8 + (c & 7);
        const int n0 = (r >> 3) * 8 + (c >> 3);
        unsigned int* p = (unsigned int*)
            &AO[(size_t)(win0 * NT + n0) * CC + head * HD + dp * 2];
        const f32x2 old = bf2_to_f32x2(*p);
        *p = cvt_pk_bf16(old.x + out2[ro].x + bias2.x,
                         old.y + out2[ro].y + bias2.y);
    }
}

// ---------------------------------------------------------------------------
// K5: proj GEMM + shortcut residual (SC, coalesced) -> X2 bf16
// ---------------------------------------------------------------------------
__global__ __launch_bounds__(256) void k_gemm_proj(const unsigned short* __restrict__ AO,
                                                   const unsigned short* __restrict__ Wp,
                                                   const unsigned short* __restrict__ bp,
                                                   const unsigned short* __restrict__ SC,
                                                   unsigned short* __restrict__ X2) {
    int m0, n0;
    xcd_tiles(blockIdx.x, 2, m0, n0);
    gemm128<256, 0>(AO, Wp, bp, m0, n0,
        [&](int m, int nb, u16x8 vals) {
            const u16x8 sc = *(const u16x8*)&SC[(size_t)m * CC + nb];
            *(u16x8*)&X2[(size_t)m * CC + nb] = add_bf8(vals, sc);
        });
}

// ---------------------------------------------------------------------------
// K6: LayerNorm2 — vectorized: half-wave per token, u16x8 loads/stores
// ---------------------------------------------------------------------------
__global__ __launch_bounds__(256) void k_ln2(const unsigned short* __restrict__ X2,
                                             const unsigned short* __restrict__ g,
                                             const unsigned short* __restrict__ bt,
                                             unsigned short* __restrict__ X2N) {
    const int tid = threadIdx.x;
    const int wv = tid >> 6, ln = tid & 63;
    const int t = blockIdx.x * 8 + wv * 2 + (ln >> 5);
    const int c8 = (ln & 31) * 8;
    const u16x8 xv = *(const u16x8*)&X2[(size_t)t * CC + c8];
    float vals[8];
    float s = 0.f, s2 = 0.f;
#pragma unroll
    for (int j = 0; j < 8; ++j) {
        const float v = b2f(xv[j]);
        vals[j] = v; s += v; s2 += v * v;
    }
#pragma unroll
    for (int off = 16; off; off >>= 1) {       // reduce within 32-lane half
        s += __shfl_xor(s, off);
        s2 += __shfl_xor(s2, off);
    }
    const float mean = s * (1.f / 256.f);
    const float rstd = rsqrtf(s2 * (1.f / 256.f) - mean * mean + 1e-5f);
    const u16x8 gv = *(const u16x8*)&g[c8];
    const u16x8 bv = *(const u16x8*)&bt[c8];
    u16x8 o;
#pragma unroll
    for (int j = 0; j < 8; j += 2) {
        const float a0 = (vals[j] - mean) * rstd * b2f(gv[j]) + b2f(bv[j]);
        const float a1 = (vals[j + 1] - mean) * rstd * b2f(gv[j + 1]) + b2f(bv[j + 1]);
        const unsigned int p = cvt_pk_bf16(a0, a1);
        o[j] = (unsigned short)p;
        o[j + 1] = (unsigned short)(p >> 16);
    }
    *(u16x8*)&X2N[(size_t)t * CC + c8] = o;
}

// ---------------------------------------------------------------------------
// K7: fc1 GEMM + GELU -> H1
// ---------------------------------------------------------------------------
__global__ __launch_bounds__(256) void k_gemm_fc1(const unsigned short* __restrict__ X2N,
                                                  const unsigned short* __restrict__ W1,
                                                  const unsigned short* __restrict__ b1,
                                                  unsigned short* __restrict__ H1) {
    int m0, n0;
    xcd_tiles(blockIdx.x, 8, m0, n0);
    gemm128<256, 1>(X2N, W1, b1, m0, n0,
        [&](int m, int nb, u16x8 vals) {
            *(u16x8*)&H1[(size_t)m * HIDN + nb] = vals;
        });
}

// ---------------------------------------------------------------------------
// K8: fc2 GEMM + trunk residual -> XOUT
// ---------------------------------------------------------------------------
__global__ __launch_bounds__(256) void k_gemm_fc2(const unsigned short* __restrict__ H1,
                                                  const unsigned short* __restrict__ W2,
                                                  const unsigned short* __restrict__ b2v,
                                                  const unsigned short* __restrict__ X2,
                                                  unsigned short* __restrict__ XOUT) {
    int m0, n0;
    xcd_tiles(blockIdx.x, 2, m0, n0);
    gemm128<1024, 0>(H1, W2, b2v, m0, n0,
        [&](int m, int nb, u16x8 vals) {
            const u16x8 r = *(const u16x8*)&X2[(size_t)m * CC + nb];
            *(u16x8*)&XOUT[(size_t)m * CC + nb] = add_bf8(vals, r);
        });
}

// ---------------------------------------------------------------------------
// K9: window reverse + transpose to (B,C,H,W). XCD-chunked + vectorized.
// ---------------------------------------------------------------------------
__global__ __launch_bounds__(256) void k_out(const unsigned short* __restrict__ XOUT,
                                             const int* __restrict__ flag,
                                             void* __restrict__ out) {
    __shared__ __align__(16) unsigned short ys[64 * 257];
    const int tid = threadIdx.x;
    const int bid = blockIdx.x;
    const int win = (bid & 7) * 128 + (bid >> 3);      // XCD-chunked
    const int b = win >> 6, wh = (win >> 3) & 7, ww = win & 7;
    for (int idx = tid; idx < 2048; idx += 256) {
        const int n = idx >> 5, c8 = (idx & 31) * 8;
        const u16x8 v = *(const u16x8*)&XOUT[(size_t)(win * NT + n) * CC + c8];
#pragma unroll
        for (int j = 0; j < 8; ++j) ys[n * 257 + c8 + j] = v[j];
    }
    __syncthreads();
    const bool f32 = (*flag != 0);
    if (f32) {
        for (int idx = tid; idx < 4096; idx += 256) {
            const int ch = idx >> 4, u = idx & 15;      // u: 4-pixel unit
            const int h = wh * 8 + (u >> 1), w = ww * 8 + (u & 1) * 4;
            const int n0 = u * 4;
            float4 v;
            v.x = b2f(ys[(n0 + 0) * 257 + ch]);
            v.y = b2f(ys[(n0 + 1) * 257 + ch]);
            v.z = b2f(ys[(n0 + 2) * 257 + ch]);
            v.w = b2f(ys[(n0 + 3) * 257 + ch]);
            *(float4*)&((float*)out)[((size_t)(b * CC + ch) * HH + h) * WW2 + w] = v;
        }
    } else {
        for (int idx = tid; idx < 2048; idx += 256) {
            const int ch = idx >> 3, u = idx & 7;       // u: 8-pixel row
            const int h = wh * 8 + u, w = ww * 8;
            const int n0 = u * 8;
            u16x8 v;
#pragma unroll
            for (int j = 0; j < 8; ++j) v[j] = ys[(n0 + j) * 257 + ch];
            *(u16x8*)&((unsigned short*)out)[((size_t)(b * CC + ch) * HH + h) * WW2 + w] = v;
        }
    }
}

// ---------------------------------------------------------------------------
extern "C" void kernel_launch(void* const* d_in, const int* in_sizes, int n_in,
                              void* d_out, int out_size, void* d_ws, size_t ws_size,
                              hipStream_t stream) {
    char* ws = (char*)d_ws;
    const size_t MB = 1048576;
    unsigned short* SC  = (unsigned short*)(ws);
    unsigned short* XN  = (unsigned short*)(ws + 32 * MB);
    unsigned short* Qb  = (unsigned short*)(ws + 64 * MB);
    unsigned short* Kb  = (unsigned short*)(ws + 96 * MB);
    unsigned short* Vb  = (unsigned short*)(ws + 128 * MB);
    unsigned short* AO  = (unsigned short*)(ws + 160 * MB);
    unsigned short* H1  = (unsigned short*)(ws + 64 * MB);
    unsigned short* X2  = (unsigned short*)(ws + 192 * MB);
    unsigned short* PAR = (unsigned short*)(ws + 224 * MB);
    int* FLAG = (int*)(ws + 224 * MB);
    unsigned short* X2N  = XN;
    unsigned short* XOUT = XN;

    ParTab tab;
    const int srcidx[15] = {3, 4, 5, 6, 7, 8, 9, 10, 11, 12, 13, 14, 15, 16, 17};
    const int sizes[15]  = {256, 256, 196608, 768, 1800, 65536, 256, 20736, 256,
                            256, 256, 262144, 1024, 262144, 256};
    const int offs[15]   = {O_N1G, O_N1B, O_QKVW, O_QKVB, O_RPB, O_PW, O_PB, O_GW, O_GB,
                            O_N2G, O_N2B, O_W1, O_B1, O_W2, O_B2};
    for (int i = 0; i < 15; ++i) {
        tab.src[i] = d_in[srcidx[i]];
        tab.n[i] = sizes[i];
        tab.off[i] = offs[i];
    }

    k_detect   <<<1,                 256, 0, stream>>>((const unsigned short*)d_in[2], FLAG);
    k_conv_par <<<dim3(64, 15),      256, 0, stream>>>(tab, FLAG, PAR);
    k_pre      <<<NWIN,              256, 0, stream>>>(d_in[2], FLAG, PAR + O_N1G, PAR + O_N1B, SC, XN);
    k_gemm_qkv <<<3072,              256, 0, stream>>>(XN, PAR + O_QKVW, PAR + O_QKVB, Qb, Kb, Vb);
    k_attn     <<<dim3(NWIN, NHD),   256, 0, stream>>>(Qb, Kb, Vb, PAR + O_RPB, AO);
    k_gaze     <<<dim3(8, 4, 128),   256, 0, stream>>>(Vb, PAR + O_GW, PAR + O_GB, AO);
    k_gemm_proj<<<1024,              256, 0, stream>>>(AO, PAR + O_PW, PAR + O_PB, SC, X2);
    k_ln2      <<<TOK / 8,           256, 0, stream>>>(X2, PAR + O_N2G, PAR + O_N2B, X2N);
    k_gemm_fc1 <<<4096,              256, 0, stream>>>(X2N, PAR + O_W1, PAR + O_B1, H1);
    k_gemm_fc2 <<<1024,              256, 0, stream>>>(H1, PAR + O_W2, PAR + O_B2, X2, XOUT);
    k_out      <<<NWIN,              256, 0, stream>>>(XOUT, FLAG, d_out);
}